// Round 4
// baseline (409.800 us; speedup 1.0000x reference)
//
#include <hip/hip_runtime.h>
#include <hip/hip_bf16.h>
#include <math.h>

#define LP 1000
#define NCMP 64

__device__ __forceinline__ float rcp_fast(float x) { return __builtin_amdgcn_rcpf(x); }

// ---------------- GEMM: Y[M,128] = op(X)[M,K] @ W[K,128] + b ----------------
// 32-row tile, 256 threads, thread = 4x4. X transposed in LDS. Software-
// pipelined: next tiles prefetched into regs at compute start (drain overlaps
// compute). MERGE: X is the 2-way KV-split flash partial pair; the m/l merge
// is applied in the X load. Requires M % 32 == 0.
template<bool RELU_IN, bool MERGE>
__global__ __launch_bounds__(256) void gemm2(const float* X, const float* X2,
                                             const float* __restrict__ mp, const float* __restrict__ lp,
                                             const float* W, const float* __restrict__ bias,
                                             float* Y, int M, int K)
{
    __shared__ __align__(16) float Ws[32][128];
    __shared__ __align__(16) float Xt[32][36];
    const int t  = threadIdx.x;
    const int r0 = (t >> 5) * 4;
    const int c0 = (t & 31) * 4;
    const int rowbase = blockIdx.x * 32;
    const int xr = t >> 3, xk = (t & 7) << 2;
    const int xrow = rowbase + xr;
    float w0 = 0.f, w1 = 0.f, linv = 0.f;
    if (MERGE) {
        const float L2E = 1.4426950408889634f;
        float m0 = mp[xrow], m1 = mp[xrow + 8000];
        float l0 = lp[xrow], l1 = lp[xrow + 8000];
        float mm = fmaxf(m0, m1);
        w0 = exp2f((m0 - mm) * L2E); w1 = exp2f((m1 - mm) * L2E);
        linv = 1.0f / (w0 * l0 + w1 * l1);
    }
    float4 xv;
    float4 wv[4];
    {   // prefetch k0 = 0
        if (MERGE) {
            long idx = (long)xrow * 128 + xk;
            float4 a = *(const float4*)(X + idx);
            float4 bb = *(const float4*)(X2 + idx);
            xv.x = (w0*a.x + w1*bb.x) * linv; xv.y = (w0*a.y + w1*bb.y) * linv;
            xv.z = (w0*a.z + w1*bb.z) * linv; xv.w = (w0*a.w + w1*bb.w) * linv;
        } else xv = *(const float4*)(X + (long)xrow * K + xk);
        if (RELU_IN) { xv.x = fmaxf(xv.x,0.f); xv.y = fmaxf(xv.y,0.f);
                       xv.z = fmaxf(xv.z,0.f); xv.w = fmaxf(xv.w,0.f); }
        #pragma unroll
        for (int u = 0; u < 4; ++u) {
            int s = t + u * 256, r = s >> 5, cb = (s & 31) << 2;
            wv[u] = *(const float4*)(W + (long)r * 128 + cb);
        }
    }
    float acc[4][4] = {};
    for (int k0 = 0; k0 < K; k0 += 32) {
        Xt[xk+0][xr] = xv.x; Xt[xk+1][xr] = xv.y; Xt[xk+2][xr] = xv.z; Xt[xk+3][xr] = xv.w;
        #pragma unroll
        for (int u = 0; u < 4; ++u) {
            int s = t + u * 256, r = s >> 5, cb = (s & 31) << 2;
            *(float4*)&Ws[r][cb] = wv[u];
        }
        __syncthreads();
        if (k0 + 32 < K) {   // prefetch next tiles; latency hidden under compute
            int kn = k0 + 32;
            if (MERGE) {
                long idx = (long)xrow * 128 + kn + xk;
                float4 a = *(const float4*)(X + idx);
                float4 bb = *(const float4*)(X2 + idx);
                xv.x = (w0*a.x + w1*bb.x) * linv; xv.y = (w0*a.y + w1*bb.y) * linv;
                xv.z = (w0*a.z + w1*bb.z) * linv; xv.w = (w0*a.w + w1*bb.w) * linv;
            } else xv = *(const float4*)(X + (long)xrow * K + kn + xk);
            if (RELU_IN) { xv.x = fmaxf(xv.x,0.f); xv.y = fmaxf(xv.y,0.f);
                           xv.z = fmaxf(xv.z,0.f); xv.w = fmaxf(xv.w,0.f); }
            #pragma unroll
            for (int u = 0; u < 4; ++u) {
                int s = t + u * 256, r = s >> 5, cb = (s & 31) << 2;
                wv[u] = *(const float4*)(W + (long)(kn + r) * 128 + cb);
            }
        }
        #pragma unroll
        for (int kk = 0; kk < 32; ++kk) {
            float4 w4 = *(const float4*)&Ws[kk][c0];
            float4 x4 = *(const float4*)&Xt[kk][r0];
            acc[0][0] = fmaf(x4.x, w4.x, acc[0][0]); acc[0][1] = fmaf(x4.x, w4.y, acc[0][1]);
            acc[0][2] = fmaf(x4.x, w4.z, acc[0][2]); acc[0][3] = fmaf(x4.x, w4.w, acc[0][3]);
            acc[1][0] = fmaf(x4.y, w4.x, acc[1][0]); acc[1][1] = fmaf(x4.y, w4.y, acc[1][1]);
            acc[1][2] = fmaf(x4.y, w4.z, acc[1][2]); acc[1][3] = fmaf(x4.y, w4.w, acc[1][3]);
            acc[2][0] = fmaf(x4.z, w4.x, acc[2][0]); acc[2][1] = fmaf(x4.z, w4.y, acc[2][1]);
            acc[2][2] = fmaf(x4.z, w4.z, acc[2][2]); acc[2][3] = fmaf(x4.z, w4.w, acc[2][3]);
            acc[3][0] = fmaf(x4.w, w4.x, acc[3][0]); acc[3][1] = fmaf(x4.w, w4.y, acc[3][1]);
            acc[3][2] = fmaf(x4.w, w4.z, acc[3][2]); acc[3][3] = fmaf(x4.w, w4.w, acc[3][3]);
        }
        __syncthreads();
    }
    float4 bv = *(const float4*)(bias + c0);
    #pragma unroll
    for (int i = 0; i < 4; ++i) {
        int row = rowbase + r0 + i;
        float4 o;
        o.x = acc[i][0] + bv.x; o.y = acc[i][1] + bv.y;
        o.z = acc[i][2] + bv.z; o.w = acc[i][3] + bv.w;
        *(float4*)(Y + (long)row * 128 + c0) = o;
    }
}

// ---------------- fused K+V GEMM: Yk|Yv = X[M,128] @ [Wk|Wv] + bk|bv ----------------
__global__ __launch_bounds__(256) void gemmKV(const float* __restrict__ X,
                                              const float* __restrict__ Wk, const float* __restrict__ Wv,
                                              const float* __restrict__ bk, const float* __restrict__ bv,
                                              float* __restrict__ Yk, float* __restrict__ Yv)
{
    __shared__ __align__(16) float Ws[32][256];
    __shared__ __align__(16) float Xt[32][36];
    const int t  = threadIdx.x;
    const int r0 = (t >> 5) * 4;
    const int c0 = (t & 31) * 4;
    const int rowbase = blockIdx.x * 32;
    const int xr = t >> 3, xk = (t & 7) << 2;
    const int xrow = rowbase + xr;
    float4 xv = *(const float4*)(X + (long)xrow * 128 + xk);
    float4 wv[8];
    #pragma unroll
    for (int u = 0; u < 8; ++u) {
        int s = t + u * 256, r = s >> 6, cb = (s & 63) << 2;
        wv[u] = (cb < 128) ? *(const float4*)(Wk + (long)r * 128 + cb)
                           : *(const float4*)(Wv + (long)r * 128 + cb - 128);
    }
    float ak[4][4] = {}, av[4][4] = {};
    for (int k0 = 0; k0 < 128; k0 += 32) {
        Xt[xk+0][xr] = xv.x; Xt[xk+1][xr] = xv.y; Xt[xk+2][xr] = xv.z; Xt[xk+3][xr] = xv.w;
        #pragma unroll
        for (int u = 0; u < 8; ++u) {
            int s = t + u * 256, r = s >> 6, cb = (s & 63) << 2;
            *(float4*)&Ws[r][cb] = wv[u];
        }
        __syncthreads();
        if (k0 + 32 < 128) {
            int kn = k0 + 32;
            xv = *(const float4*)(X + (long)xrow * 128 + kn + xk);
            #pragma unroll
            for (int u = 0; u < 8; ++u) {
                int s = t + u * 256, r = s >> 6, cb = (s & 63) << 2;
                wv[u] = (cb < 128) ? *(const float4*)(Wk + (long)(kn + r) * 128 + cb)
                                   : *(const float4*)(Wv + (long)(kn + r) * 128 + cb - 128);
            }
        }
        #pragma unroll
        for (int kk = 0; kk < 32; ++kk) {
            float4 x4 = *(const float4*)&Xt[kk][r0];
            float4 k4 = *(const float4*)&Ws[kk][c0];
            float4 v4 = *(const float4*)&Ws[kk][128 + c0];
            #pragma unroll
            for (int i = 0; i < 4; ++i) {
                float xi = (i==0)?x4.x:(i==1)?x4.y:(i==2)?x4.z:x4.w;
                ak[i][0] = fmaf(xi, k4.x, ak[i][0]); ak[i][1] = fmaf(xi, k4.y, ak[i][1]);
                ak[i][2] = fmaf(xi, k4.z, ak[i][2]); ak[i][3] = fmaf(xi, k4.w, ak[i][3]);
                av[i][0] = fmaf(xi, v4.x, av[i][0]); av[i][1] = fmaf(xi, v4.y, av[i][1]);
                av[i][2] = fmaf(xi, v4.z, av[i][2]); av[i][3] = fmaf(xi, v4.w, av[i][3]);
            }
        }
        __syncthreads();
    }
    float4 bk4 = *(const float4*)(bk + c0);
    float4 bv4 = *(const float4*)(bv + c0);
    #pragma unroll
    for (int i = 0; i < 4; ++i) {
        int row = rowbase + r0 + i;
        float4 ok, ov;
        ok.x = ak[i][0]+bk4.x; ok.y = ak[i][1]+bk4.y; ok.z = ak[i][2]+bk4.z; ok.w = ak[i][3]+bk4.w;
        ov.x = av[i][0]+bv4.x; ov.y = av[i][1]+bv4.y; ov.z = av[i][2]+bv4.z; ov.w = av[i][3]+bv4.w;
        *(float4*)(Yk + (long)row * 128 + c0) = ok;
        *(float4*)(Yv + (long)row * 128 + c0) = ov;
    }
}

// ---------------- b' = emb_b @ wq_w + wq_b ----------------
__global__ __launch_bounds__(128) void bprime_k(const float* __restrict__ eb, const float* __restrict__ wqw,
                                                const float* __restrict__ wqb, float* __restrict__ bp)
{
    int n = threadIdx.x;
    float a0 = 0.f, a1 = 0.f, a2 = 0.f, a3 = 0.f;
    for (int k = 0; k < 128; k += 4) {
        a0 = fmaf(eb[k+0], wqw[(k+0)*128 + n], a0);
        a1 = fmaf(eb[k+1], wqw[(k+1)*128 + n], a1);
        a2 = fmaf(eb[k+2], wqw[(k+2)*128 + n], a2);
        a3 = fmaf(eb[k+3], wqw[(k+3)*128 + n], a3);
    }
    bp[n] = (a0 + a1) + (a2 + a3) + wqb[n];
}

// ---------------- flash attention v2 (fp32), TQ=32, TK=64, split x2 ----------------
// 128 threads. Thread: 4 q-rows (rg*4+i) x 4 k-cols (cl+16j) for QK; 4 rows x
// 8 dcols (cl*4, 64+cl*4) for PV. Q read straight from global (L1-resident
// 16KB tile) - zero Q LDS traffic. P stored transposed Pt[c][row] so PV reads
// it as one b128. V global loads for kt+1 issued at PV(kt) start: their drain
// at the next barrier lands after ~2300 cyc of LDS compute (latency hidden).
__global__ __launch_bounds__(128) void flash2_k(const float* __restrict__ Q, const float* __restrict__ Kg,
                                                const float* __restrict__ Vg, float* __restrict__ Opart,
                                                float* __restrict__ mpart, float* __restrict__ lpart)
{
    __shared__ __align__(16) float KVs[64][132];
    __shared__ __align__(16) float Pt[64][36];
    const int t  = threadIdx.x;
    const int rg = t >> 4;     // 0..7
    const int cl = t & 15;
    const int qt = blockIdx.x, sp = blockIdx.y, b = blockIdx.z;
    const int q0 = qt * 32;
    const float SCALE = 0.08838834764831845f;   // 1/sqrt(128)
    const float L2E   = 1.4426950408889634f;
    const float* Qb = Q + ((long)b * LP + q0 + rg * 4) * 128;

    float m_i[4] = { -3.0e38f, -3.0e38f, -3.0e38f, -3.0e38f };
    float l_i[4] = { 0.f, 0.f, 0.f, 0.f };
    float Oa[4][8] = {};
    float4 vreg[16];

    {   // prologue: V loads for first kt (drained at first barrier B)
        const int key0 = sp * 512;
        #pragma unroll
        for (int u = 0; u < 16; ++u) {
            int s = t + u * 128, r = s >> 5, cb = (s & 31) << 2;
            vreg[u] = make_float4(0.f, 0.f, 0.f, 0.f);
            if (key0 + r < LP) vreg[u] = *(const float4*)(Vg + ((long)b * LP + key0 + r) * 128 + cb);
        }
    }

    for (int kt = sp * 8; kt < sp * 8 + 8; ++kt) {
        const int key0 = kt * 64;
        __syncthreads();                            // (A) prev PV done -> KVs free
        #pragma unroll
        for (int u = 0; u < 16; ++u) {              // stage K 64x128
            int s = t + u * 128, r = s >> 5, cb = (s & 31) << 2;
            float4 v = make_float4(0.f, 0.f, 0.f, 0.f);
            if (key0 + r < LP) v = *(const float4*)(Kg + ((long)b * LP + key0 + r) * 128 + cb);
            KVs[r][cb] = v.x; KVs[r][cb+1] = v.y; KVs[r][cb+2] = v.z; KVs[r][cb+3] = v.w;
        }
        __syncthreads();                            // (B) K visible
        float sacc[4][4] = {};
        #pragma unroll 4
        for (int d4 = 0; d4 < 32; ++d4) {
            float4 qv0 = *(const float4*)(Qb + 0 * 128 + (d4 << 2));
            float4 qv1 = *(const float4*)(Qb + 1 * 128 + (d4 << 2));
            float4 qv2 = *(const float4*)(Qb + 2 * 128 + (d4 << 2));
            float4 qv3 = *(const float4*)(Qb + 3 * 128 + (d4 << 2));
            #pragma unroll
            for (int j = 0; j < 4; ++j) {
                float4 kv = *(const float4*)&KVs[cl + (j << 4)][d4 << 2];
                sacc[0][j] += qv0.x*kv.x + qv0.y*kv.y + qv0.z*kv.z + qv0.w*kv.w;
                sacc[1][j] += qv1.x*kv.x + qv1.y*kv.y + qv1.z*kv.z + qv1.w*kv.w;
                sacc[2][j] += qv2.x*kv.x + qv2.y*kv.y + qv2.z*kv.z + qv2.w*kv.w;
                sacc[3][j] += qv3.x*kv.x + qv3.y*kv.y + qv3.z*kv.z + qv3.w*kv.w;
            }
        }
        // scale + mask
        #pragma unroll
        for (int j = 0; j < 4; ++j) {
            bool valid = (key0 + cl + (j << 4)) < LP;
            #pragma unroll
            for (int i = 0; i < 4; ++i) {
                float sv = sacc[i][j] * SCALE;
                sacc[i][j] = valid ? sv : -3.0e38f;
            }
        }
        float alpha[4];
        #pragma unroll
        for (int i = 0; i < 4; ++i) {   // online softmax; 16-lane groups share rows
            float tm = fmaxf(fmaxf(sacc[i][0], sacc[i][1]), fmaxf(sacc[i][2], sacc[i][3]));
            tm = fmaxf(tm, __shfl_xor(tm, 1));
            tm = fmaxf(tm, __shfl_xor(tm, 2));
            tm = fmaxf(tm, __shfl_xor(tm, 4));
            tm = fmaxf(tm, __shfl_xor(tm, 8));
            float mnew = fmaxf(m_i[i], tm);
            alpha[i] = exp2f((m_i[i] - mnew) * L2E);
            float ps = 0.f;
            #pragma unroll
            for (int j = 0; j < 4; ++j) {
                float p = exp2f((sacc[i][j] - mnew) * L2E);
                sacc[i][j] = p;
                ps += p;
            }
            ps += __shfl_xor(ps, 1);
            ps += __shfl_xor(ps, 2);
            ps += __shfl_xor(ps, 4);
            ps += __shfl_xor(ps, 8);
            l_i[i] = l_i[i] * alpha[i] + ps;
            m_i[i] = mnew;
            #pragma unroll
            for (int j = 0; j < 8; ++j) Oa[i][j] *= alpha[i];
        }
        __syncthreads();                            // (C) K reads done
        #pragma unroll
        for (int u = 0; u < 16; ++u) {              // V regs -> LDS (overwrite K)
            int s = t + u * 128, r = s >> 5, cb = (s & 31) << 2;
            KVs[r][cb] = vreg[u].x; KVs[r][cb+1] = vreg[u].y;
            KVs[r][cb+2] = vreg[u].z; KVs[r][cb+3] = vreg[u].w;
        }
        #pragma unroll
        for (int j = 0; j < 4; ++j)                 // P -> Pt[c][row] (b128 per col)
            *(float4*)&Pt[cl + (j << 4)][rg * 4] =
                make_float4(sacc[0][j], sacc[1][j], sacc[2][j], sacc[3][j]);
        __syncthreads();                            // (D) V + Pt visible
        if (kt + 1 < sp * 8 + 8) {                  // prefetch V for kt+1 under PV
            const int kn0 = (kt + 1) * 64;
            #pragma unroll
            for (int u = 0; u < 16; ++u) {
                int s = t + u * 128, r = s >> 5, cb = (s & 31) << 2;
                vreg[u] = make_float4(0.f, 0.f, 0.f, 0.f);
                if (kn0 + r < LP) vreg[u] = *(const float4*)(Vg + ((long)b * LP + kn0 + r) * 128 + cb);
            }
        }
        #pragma unroll 2
        for (int c = 0; c < 64; ++c) {              // PV
            float4 p4 = *(const float4*)&Pt[c][rg * 4];
            float4 va = *(const float4*)&KVs[c][cl * 4];
            float4 vb = *(const float4*)&KVs[c][64 + cl * 4];
            Oa[0][0] = fmaf(p4.x, va.x, Oa[0][0]); Oa[0][1] = fmaf(p4.x, va.y, Oa[0][1]);
            Oa[0][2] = fmaf(p4.x, va.z, Oa[0][2]); Oa[0][3] = fmaf(p4.x, va.w, Oa[0][3]);
            Oa[0][4] = fmaf(p4.x, vb.x, Oa[0][4]); Oa[0][5] = fmaf(p4.x, vb.y, Oa[0][5]);
            Oa[0][6] = fmaf(p4.x, vb.z, Oa[0][6]); Oa[0][7] = fmaf(p4.x, vb.w, Oa[0][7]);
            Oa[1][0] = fmaf(p4.y, va.x, Oa[1][0]); Oa[1][1] = fmaf(p4.y, va.y, Oa[1][1]);
            Oa[1][2] = fmaf(p4.y, va.z, Oa[1][2]); Oa[1][3] = fmaf(p4.y, va.w, Oa[1][3]);
            Oa[1][4] = fmaf(p4.y, vb.x, Oa[1][4]); Oa[1][5] = fmaf(p4.y, vb.y, Oa[1][5]);
            Oa[1][6] = fmaf(p4.y, vb.z, Oa[1][6]); Oa[1][7] = fmaf(p4.y, vb.w, Oa[1][7]);
            Oa[2][0] = fmaf(p4.z, va.x, Oa[2][0]); Oa[2][1] = fmaf(p4.z, va.y, Oa[2][1]);
            Oa[2][2] = fmaf(p4.z, va.z, Oa[2][2]); Oa[2][3] = fmaf(p4.z, va.w, Oa[2][3]);
            Oa[2][4] = fmaf(p4.z, vb.x, Oa[2][4]); Oa[2][5] = fmaf(p4.z, vb.y, Oa[2][5]);
            Oa[2][6] = fmaf(p4.z, vb.z, Oa[2][6]); Oa[2][7] = fmaf(p4.z, vb.w, Oa[2][7]);
            Oa[3][0] = fmaf(p4.w, va.x, Oa[3][0]); Oa[3][1] = fmaf(p4.w, va.y, Oa[3][1]);
            Oa[3][2] = fmaf(p4.w, va.z, Oa[3][2]); Oa[3][3] = fmaf(p4.w, va.w, Oa[3][3]);
            Oa[3][4] = fmaf(p4.w, vb.x, Oa[3][4]); Oa[3][5] = fmaf(p4.w, vb.y, Oa[3][5]);
            Oa[3][6] = fmaf(p4.w, vb.z, Oa[3][6]); Oa[3][7] = fmaf(p4.w, vb.w, Oa[3][7]);
        }
    }
    #pragma unroll
    for (int i = 0; i < 4; ++i) {
        int row = q0 + rg * 4 + i;
        if (row < LP) {
            long base = (((long)sp * 8 + b) * LP + row) * 128;
            *(float4*)(Opart + base + cl * 4)      = make_float4(Oa[i][0], Oa[i][1], Oa[i][2], Oa[i][3]);
            *(float4*)(Opart + base + 64 + cl * 4) = make_float4(Oa[i][4], Oa[i][5], Oa[i][6], Oa[i][7]);
            if (cl == 0) {
                mpart[((long)sp * 8 + b) * LP + row] = m_i[i];
                lpart[((long)sp * 8 + b) * LP + row] = l_i[i];
            }
        }
    }
}

// -------- fused: A = sigmoid(P C^T) (kept in LDS) + Asum + tanh outer-product reduce --------
__global__ __launch_bounds__(256) void sigcp_k(const float* __restrict__ P, const float* __restrict__ Cj,
                                               const float* __restrict__ pf, const float* __restrict__ cf,
                                               float* __restrict__ Asum, float* __restrict__ cpe)
{
    __shared__ __align__(16) float Psh[32][132];
    __shared__ __align__(16) float Csh[64][132];
    __shared__ float Ash[32][64];
    __shared__ float red[256];
    const int t  = threadIdx.x;
    const int tr = t >> 4, tc = t & 15;
    const int i0 = blockIdx.x * 32;
    const int b  = blockIdx.y;
    // ---- phase 1: sigmoid bilinear tile ----
    #pragma unroll
    for (int u = 0; u < 4; ++u) {
        int s = t + u * 256, r = s >> 5, cb = (s & 31) << 2;
        float4 v = make_float4(0.f, 0.f, 0.f, 0.f);
        if (i0 + r < LP) v = *(const float4*)(P + ((long)b * LP + i0 + r) * 128 + cb);
        Psh[r][cb] = v.x; Psh[r][cb+1] = v.y; Psh[r][cb+2] = v.z; Psh[r][cb+3] = v.w;
    }
    #pragma unroll
    for (int u = 0; u < 8; ++u) {
        int s = t + u * 256, r = s >> 5, cb = (s & 31) << 2;
        float4 v = *(const float4*)(Cj + ((long)b * NCMP + r) * 128 + cb);
        Csh[r][cb] = v.x; Csh[r][cb+1] = v.y; Csh[r][cb+2] = v.z; Csh[r][cb+3] = v.w;
    }
    __syncthreads();
    float sacc[2][4] = {};
    #pragma unroll 4
    for (int d4 = 0; d4 < 32; ++d4) {
        float4 p0 = *(const float4*)&Psh[2 * tr][d4 << 2];
        float4 p1 = *(const float4*)&Psh[2 * tr + 1][d4 << 2];
        #pragma unroll
        for (int j = 0; j < 4; ++j) {
            float4 cv = *(const float4*)&Csh[tc + (j << 4)][d4 << 2];
            sacc[0][j] += p0.x*cv.x + p0.y*cv.y + p0.z*cv.z + p0.w*cv.w;
            sacc[1][j] += p1.x*cv.x + p1.y*cv.y + p1.z*cv.z + p1.w*cv.w;
        }
    }
    const float L2E = 1.4426950408889634f;
    float lsum = 0.f;
    #pragma unroll
    for (int i = 0; i < 2; ++i) {
        int gi = i0 + 2 * tr + i;
        #pragma unroll
        for (int j = 0; j < 4; ++j) {
            float sg = rcp_fast(1.f + exp2f(-sacc[i][j] * L2E));
            if (gi < LP) { Ash[2 * tr + i][tc + (j << 4)] = sg; lsum += sg; }
        }
    }
    red[t] = lsum;
    __syncthreads();
    for (int off = 128; off > 0; off >>= 1) {
        if (t < off) red[t] += red[t + off];
        __syncthreads();
    }
    if (t == 0) atomicAdd(Asum + b, red[0]);
    // ---- phase 2: cpe partial (Csh reloaded with raw compound feats) ----
    __syncthreads();
    #pragma unroll
    for (int u = 0; u < 8; ++u) {
        int s = t + u * 256, r = s >> 5, cb = (s & 31) << 2;
        float4 v = *(const float4*)(cf + ((long)b * NCMP + r) * 128 + cb);
        Csh[r][cb] = v.x; Csh[r][cb+1] = v.y; Csh[r][cb+2] = v.z; Csh[r][cb+3] = v.w;
    }
    __syncthreads();
    const float TWO_L2E = 2.8853900817779268f;   // 2*log2(e)
    const int d  = t & 127;
    const int kh = t >> 7;
    const int iiN = (LP - i0 < 32) ? (LP - i0) : 32;
    float acc = 0.f;
    for (int ii = 0; ii < iiN; ++ii) {
        float pv  = pf[((long)b * LP + i0 + ii) * 128 + d];
        float ptl = pv * TWO_L2E;
        #pragma unroll
        for (int kk = 0; kk < 32; ++kk) {
            int k = (kh << 5) + kk;
            float e  = exp2f(ptl * Csh[k][d]);          // exp(2x)
            float th = 1.f - 2.f * rcp_fast(e + 1.f);   // tanh(x)
            acc = fmaf(th, Ash[ii][k], acc);
        }
    }
    red[t] = acc;
    __syncthreads();
    if (t < 128) atomicAdd(cpe + (long)b * 128 + t, red[t] + red[t + 128]);
}

// ---------------- classifier MLP: split-K partial kernels + finalize ----------------
__global__ __launch_bounds__(256) void c1_part_k(const float* __restrict__ cpe, const float* __restrict__ Asum,
                                                 const float* __restrict__ W, float* __restrict__ part)
{
    __shared__ float ins[8][8];
    const int t = threadIdx.x, ks = blockIdx.x, k0 = ks * 8;
    if (t < 64) {
        int b = t >> 3, kk = t & 7;
        ins[b][kk] = cpe[b * 128 + k0 + kk] * (1.0f / Asum[b]);
    }
    __syncthreads();
    const int n = (t & 63) * 4 + (t >> 6) * 256;
    float4 acc[8] = {};
    #pragma unroll
    for (int kk = 0; kk < 8; ++kk) {
        float4 w4 = *(const float4*)(W + (long)(k0 + kk) * 1024 + n);
        #pragma unroll
        for (int b = 0; b < 8; ++b) {
            float s = ins[b][kk];
            acc[b].x = fmaf(s, w4.x, acc[b].x); acc[b].y = fmaf(s, w4.y, acc[b].y);
            acc[b].z = fmaf(s, w4.z, acc[b].z); acc[b].w = fmaf(s, w4.w, acc[b].w);
        }
    }
    #pragma unroll
    for (int b = 0; b < 8; ++b)
        *(float4*)(part + ((long)(ks * 8 + b)) * 1024 + n) = acc[b];
}

__global__ __launch_bounds__(256) void c2_part_k(const float* __restrict__ in, const float* __restrict__ W,
                                                 float* __restrict__ part)
{
    __shared__ float ins[8][16];
    const int t = threadIdx.x, ks = blockIdx.x, k0 = ks * 16;
    if (t < 128) {
        int b = t >> 4, kk = t & 15;
        ins[b][kk] = in[b * 1024 + k0 + kk];
    }
    __syncthreads();
    const int n = (t & 63) * 4 + (t >> 6) * 256;
    float4 acc[8] = {};
    #pragma unroll
    for (int kk = 0; kk < 16; ++kk) {
        float4 w4 = *(const float4*)(W + (long)(k0 + kk) * 1024 + n);
        #pragma unroll
        for (int b = 0; b < 8; ++b) {
            float s = ins[b][kk];
            acc[b].x = fmaf(s, w4.x, acc[b].x); acc[b].y = fmaf(s, w4.y, acc[b].y);
            acc[b].z = fmaf(s, w4.z, acc[b].z); acc[b].w = fmaf(s, w4.w, acc[b].w);
        }
    }
    #pragma unroll
    for (int b = 0; b < 8; ++b)
        *(float4*)(part + ((long)(ks * 8 + b)) * 1024 + n) = acc[b];
}

__global__ __launch_bounds__(256) void c3_part_k(const float* __restrict__ in, const float* __restrict__ W,
                                                 float* __restrict__ part)
{
    __shared__ float ins[8][64];
    const int t = threadIdx.x, bid = blockIdx.x;
    {
        int s0 = t, b = s0 >> 6, kk = s0 & 63;
        ins[b][kk] = in[b * 1024 + bid * 64 + kk];
        int s1 = t + 256; b = s1 >> 6; kk = s1 & 63;
        ins[b][kk] = in[b * 1024 + bid * 64 + kk];
    }
    __syncthreads();
    const int kq = t >> 6;
    const int n  = (t & 63) * 4;
    const int kbase = bid * 64 + kq * 16;
    float4 acc[8] = {};
    #pragma unroll
    for (int kk = 0; kk < 16; ++kk) {
        float4 w4 = *(const float4*)(W + (long)(kbase + kk) * 256 + n);
        #pragma unroll
        for (int b = 0; b < 8; ++b) {
            float s = ins[b][kq * 16 + kk];
            acc[b].x = fmaf(s, w4.x, acc[b].x); acc[b].y = fmaf(s, w4.y, acc[b].y);
            acc[b].z = fmaf(s, w4.z, acc[b].z); acc[b].w = fmaf(s, w4.w, acc[b].w);
        }
    }
    const int ks = bid * 4 + kq;
    #pragma unroll
    for (int b = 0; b < 8; ++b)
        *(float4*)(part + ((long)(ks * 8 + b)) * 256 + n) = acc[b];
}

template<int N, int KS>
__global__ __launch_bounds__(256) void mlp_fin_k(const float* __restrict__ part, const float* __restrict__ bias,
                                                 float* __restrict__ out)
{
    int idx = blockIdx.x * 256 + threadIdx.x;
    int n = idx % N;
    float acc = 0.f;
    #pragma unroll 4
    for (int ks = 0; ks < KS; ++ks) acc += part[(long)ks * 8 * N + idx];
    out[idx] = fmaxf(acc + bias[n], 0.f);
}

__global__ __launch_bounds__(256) void mlp4_k(const float* __restrict__ h3, const float* __restrict__ W,
                                              const float* __restrict__ bias, float* __restrict__ out)
{
    int t = threadIdx.x;
    int b = t >> 5, l = t & 31;
    float acc = 0.f;
    for (int k = l; k < 256; k += 32) acc = fmaf(h3[b * 256 + k], W[k], acc);
    #pragma unroll
    for (int off = 16; off > 0; off >>= 1) acc += __shfl_xor(acc, off);
    if (l == 0) out[b] = acc + bias[0];
}

extern "C" void kernel_launch(void* const* d_in, const int* in_sizes, int n_in,
                              void* d_out, int out_size, void* d_ws, size_t ws_size,
                              hipStream_t stream)
{
    const float* PE   = (const float*)d_in[0];
    const float* PFX  = (const float*)d_in[1];
    const float* CF   = (const float*)d_in[2];
    const float* emb_w = (const float*)d_in[3];  const float* emb_b = (const float*)d_in[4];
    const float* wq_w  = (const float*)d_in[5];  const float* wq_b  = (const float*)d_in[6];
    const float* wk_w  = (const float*)d_in[7];  const float* wk_b  = (const float*)d_in[8];
    const float* wv_w  = (const float*)d_in[9];  const float* wv_b  = (const float*)d_in[10];
    const float* wo_w  = (const float*)d_in[11]; const float* wo_b  = (const float*)d_in[12];
    const float* jp_w  = (const float*)d_in[13]; const float* jp_b  = (const float*)d_in[14];
    const float* jc_w  = (const float*)d_in[15]; const float* jc_b  = (const float*)d_in[16];
    const float* c1_w  = (const float*)d_in[17]; const float* c1_b  = (const float*)d_in[18];
    const float* c2_w  = (const float*)d_in[19]; const float* c2_b  = (const float*)d_in[20];
    const float* c3_w  = (const float*)d_in[21]; const float* c3_b  = (const float*)d_in[22];
    const float* c4_w  = (const float*)d_in[23]; const float* c4_b  = (const float*)d_in[24];

    float* ws     = (float*)d_ws;
    float* bufQ   = ws;                    // 1,024,000
    float* bufK   = bufQ   + 1024000;      // 1,024,000
    float* bufV   = bufK   + 1024000;      // 1,024,000
    float* bufAtt = bufV   + 1024000;      // 1,024,000 (protein_feats)
    float* bufP   = bufAtt + 1024000;      // 1,024,000
    float* bufC   = bufP   + 1024000;      //    65,536
    float* Opart  = bufC   + 65536;        // 2,048,000 (flash partials; later MLP partials)
    float* mpart  = Opart  + 2048000;      //    16,000
    float* lpart  = mpart  + 16000;        //    16,000
    float* Asum   = lpart  + 16000;        //         8
    float* cpe    = Asum   + 8;            //     1,024
    float* zeros  = cpe    + 1024;         //       128
    float* bprime = zeros  + 128;          //       128
    float* bufWp  = bprime + 128;          //    40,960  (emb_w @ wq_w)
    float* h1     = bufWp  + 40960;        //     8,192
    float* h2     = h1     + 8192;         //     8,192
    float* h3     = h2     + 8192;         //     2,048
    // MLP split-K partials alias Opart (dead after the wo gemm):
    float* part1  = Opart;                 //  16*8192
    float* part2  = part1  + 131072;       //  64*8192
    float* part3  = part2  + 524288;       //  64*2048
    // total ~7.4M floats = ~29.5 MB

    hipMemsetAsync(Asum, 0, (8 + 1024 + 128) * sizeof(float), stream);   // Asum, cpe, zeros

    bprime_k<<<1, 128, 0, stream>>>(emb_b, wq_w, wq_b, bprime);
    gemm2<false,false><<<10, 256, 0, stream>>>(emb_w, nullptr, nullptr, nullptr,
                                               wq_w, zeros, bufWp, 320, 128);       // W' = emb_w @ wq_w
    gemm2<false,false><<<250, 256, 0, stream>>>(PE, nullptr, nullptr, nullptr,
                                                bufWp, bprime, bufQ, 8000, 320);    // Q = PE @ W' + b'
    gemmKV<<<250, 256, 0, stream>>>(PFX, wk_w, wv_w, wk_b, wv_b, bufK, bufV);       // K, V fused
    flash2_k<<<dim3(32, 2, 8), 128, 0, stream>>>(bufQ, bufK, bufV, Opart, mpart, lpart);
    gemm2<false,true ><<<250, 256, 0, stream>>>(Opart, Opart + 1024000, mpart, lpart,
                                                wo_w, wo_b, bufAtt, 8000, 128);     // wo + split merge
    gemm2<true ,false><<<250, 256, 0, stream>>>(bufAtt, nullptr, nullptr, nullptr,
                                                jp_w, jp_b, bufP, 8000, 128);       // P
    gemm2<true ,false><<<16,  256, 0, stream>>>(CF, nullptr, nullptr, nullptr,
                                                jc_w, jc_b, bufC, 512, 128);        // C
    sigcp_k<<<dim3(32, 8), 256, 0, stream>>>(bufP, bufC, bufAtt, CF, Asum, cpe);
    c1_part_k<<<16, 256, 0, stream>>>(cpe, Asum, c1_w, part1);
    mlp_fin_k<1024, 16><<<32, 256, 0, stream>>>(part1, c1_b, h1);
    c2_part_k<<<64, 256, 0, stream>>>(h1, c2_w, part2);
    mlp_fin_k<1024, 64><<<32, 256, 0, stream>>>(part2, c2_b, h2);
    c3_part_k<<<16, 256, 0, stream>>>(h2, c3_w, part3);
    mlp_fin_k<256, 64><<<8, 256, 0, stream>>>(part3, c3_b, h3);
    mlp4_k<<<1, 256, 0, stream>>>(h3, c4_w, c4_b, (float*)d_out);
}

// Round 5
// 382.706 us; speedup vs baseline: 1.0708x; 1.0708x over previous
//
#include <hip/hip_runtime.h>
#include <hip/hip_bf16.h>
#include <math.h>

#define LP 1000
#define NCMP 64

__device__ __forceinline__ float rcp_fast(float x) { return __builtin_amdgcn_rcpf(x); }

// ---------------- GEMM body: Y[M,128] = op(X)[M,K] @ W[K,128] + b ----------------
// 32-row tile, 256 threads, thread = 4x4, X transposed in LDS, software-pipelined.
// MERGE: X/X2 are the KV-split flash partials, m/l merge applied on load.
template<bool RELU_IN, bool MERGE>
__device__ __forceinline__ void gemm_body(const float* X, const float* X2,
                                          const float* __restrict__ mp, const float* __restrict__ lp,
                                          const float* W, const float* __restrict__ bias,
                                          float* Y, int K, int rowbase)
{
    __shared__ __align__(16) float Ws[32][128];
    __shared__ __align__(16) float Xt[32][36];
    const int t  = threadIdx.x;
    const int r0 = (t >> 5) * 4;
    const int c0 = (t & 31) * 4;
    const int xr = t >> 3, xk = (t & 7) << 2;
    const int xrow = rowbase + xr;
    float w0 = 0.f, w1 = 0.f, linv = 0.f;
    if (MERGE) {
        const float L2E = 1.4426950408889634f;
        float m0 = mp[xrow], m1 = mp[xrow + 8000];
        float l0 = lp[xrow], l1 = lp[xrow + 8000];
        float mm = fmaxf(m0, m1);
        w0 = exp2f((m0 - mm) * L2E); w1 = exp2f((m1 - mm) * L2E);
        linv = 1.0f / (w0 * l0 + w1 * l1);
    }
    float4 xv;
    float4 wv[4];
    {
        if (MERGE) {
            long idx = (long)xrow * 128 + xk;
            float4 a = *(const float4*)(X + idx);
            float4 bb = *(const float4*)(X2 + idx);
            xv.x = (w0*a.x + w1*bb.x) * linv; xv.y = (w0*a.y + w1*bb.y) * linv;
            xv.z = (w0*a.z + w1*bb.z) * linv; xv.w = (w0*a.w + w1*bb.w) * linv;
        } else xv = *(const float4*)(X + (long)xrow * K + xk);
        if (RELU_IN) { xv.x = fmaxf(xv.x,0.f); xv.y = fmaxf(xv.y,0.f);
                       xv.z = fmaxf(xv.z,0.f); xv.w = fmaxf(xv.w,0.f); }
        #pragma unroll
        for (int u = 0; u < 4; ++u) {
            int s = t + u * 256, r = s >> 5, cb = (s & 31) << 2;
            wv[u] = *(const float4*)(W + (long)r * 128 + cb);
        }
    }
    float acc[4][4] = {};
    for (int k0 = 0; k0 < K; k0 += 32) {
        Xt[xk+0][xr] = xv.x; Xt[xk+1][xr] = xv.y; Xt[xk+2][xr] = xv.z; Xt[xk+3][xr] = xv.w;
        #pragma unroll
        for (int u = 0; u < 4; ++u) {
            int s = t + u * 256, r = s >> 5, cb = (s & 31) << 2;
            *(float4*)&Ws[r][cb] = wv[u];
        }
        __syncthreads();
        if (k0 + 32 < K) {
            int kn = k0 + 32;
            if (MERGE) {
                long idx = (long)xrow * 128 + kn + xk;
                float4 a = *(const float4*)(X + idx);
                float4 bb = *(const float4*)(X2 + idx);
                xv.x = (w0*a.x + w1*bb.x) * linv; xv.y = (w0*a.y + w1*bb.y) * linv;
                xv.z = (w0*a.z + w1*bb.z) * linv; xv.w = (w0*a.w + w1*bb.w) * linv;
            } else xv = *(const float4*)(X + (long)xrow * K + kn + xk);
            if (RELU_IN) { xv.x = fmaxf(xv.x,0.f); xv.y = fmaxf(xv.y,0.f);
                           xv.z = fmaxf(xv.z,0.f); xv.w = fmaxf(xv.w,0.f); }
            #pragma unroll
            for (int u = 0; u < 4; ++u) {
                int s = t + u * 256, r = s >> 5, cb = (s & 31) << 2;
                wv[u] = *(const float4*)(W + (long)(kn + r) * 128 + cb);
            }
        }
        #pragma unroll
        for (int kk = 0; kk < 32; ++kk) {
            float4 w4 = *(const float4*)&Ws[kk][c0];
            float4 x4 = *(const float4*)&Xt[kk][r0];
            acc[0][0] = fmaf(x4.x, w4.x, acc[0][0]); acc[0][1] = fmaf(x4.x, w4.y, acc[0][1]);
            acc[0][2] = fmaf(x4.x, w4.z, acc[0][2]); acc[0][3] = fmaf(x4.x, w4.w, acc[0][3]);
            acc[1][0] = fmaf(x4.y, w4.x, acc[1][0]); acc[1][1] = fmaf(x4.y, w4.y, acc[1][1]);
            acc[1][2] = fmaf(x4.y, w4.z, acc[1][2]); acc[1][3] = fmaf(x4.y, w4.w, acc[1][3]);
            acc[2][0] = fmaf(x4.z, w4.x, acc[2][0]); acc[2][1] = fmaf(x4.z, w4.y, acc[2][1]);
            acc[2][2] = fmaf(x4.z, w4.z, acc[2][2]); acc[2][3] = fmaf(x4.z, w4.w, acc[2][3]);
            acc[3][0] = fmaf(x4.w, w4.x, acc[3][0]); acc[3][1] = fmaf(x4.w, w4.y, acc[3][1]);
            acc[3][2] = fmaf(x4.w, w4.z, acc[3][2]); acc[3][3] = fmaf(x4.w, w4.w, acc[3][3]);
        }
        __syncthreads();
    }
    float4 bv = *(const float4*)(bias + c0);
    #pragma unroll
    for (int i = 0; i < 4; ++i) {
        int row = rowbase + r0 + i;
        float4 o;
        o.x = acc[i][0] + bv.x; o.y = acc[i][1] + bv.y;
        o.z = acc[i][2] + bv.z; o.w = acc[i][3] + bv.w;
        *(float4*)(Y + (long)row * 128 + c0) = o;
    }
}

// ---------------- dual-output K|V GEMM body ----------------
__device__ __forceinline__ void kv_body(const float* __restrict__ X,
                                        const float* __restrict__ Wk, const float* __restrict__ Wv,
                                        const float* __restrict__ bk, const float* __restrict__ bv,
                                        float* __restrict__ Yk, float* __restrict__ Yv, int rowbase)
{
    __shared__ __align__(16) float Ws2[32][256];
    __shared__ __align__(16) float Xt2[32][36];
    const int t  = threadIdx.x;
    const int r0 = (t >> 5) * 4;
    const int c0 = (t & 31) * 4;
    const int xr = t >> 3, xk = (t & 7) << 2;
    const int xrow = rowbase + xr;
    float4 xv = *(const float4*)(X + (long)xrow * 128 + xk);
    float4 wv[8];
    #pragma unroll
    for (int u = 0; u < 8; ++u) {
        int s = t + u * 256, r = s >> 6, cb = (s & 63) << 2;
        wv[u] = (cb < 128) ? *(const float4*)(Wk + (long)r * 128 + cb)
                           : *(const float4*)(Wv + (long)r * 128 + cb - 128);
    }
    float ak[4][4] = {}, av[4][4] = {};
    for (int k0 = 0; k0 < 128; k0 += 32) {
        Xt2[xk+0][xr] = xv.x; Xt2[xk+1][xr] = xv.y; Xt2[xk+2][xr] = xv.z; Xt2[xk+3][xr] = xv.w;
        #pragma unroll
        for (int u = 0; u < 8; ++u) {
            int s = t + u * 256, r = s >> 6, cb = (s & 63) << 2;
            *(float4*)&Ws2[r][cb] = wv[u];
        }
        __syncthreads();
        if (k0 + 32 < 128) {
            int kn = k0 + 32;
            xv = *(const float4*)(X + (long)xrow * 128 + kn + xk);
            #pragma unroll
            for (int u = 0; u < 8; ++u) {
                int s = t + u * 256, r = s >> 6, cb = (s & 63) << 2;
                wv[u] = (cb < 128) ? *(const float4*)(Wk + (long)(kn + r) * 128 + cb)
                                   : *(const float4*)(Wv + (long)(kn + r) * 128 + cb - 128);
            }
        }
        #pragma unroll
        for (int kk = 0; kk < 32; ++kk) {
            float4 x4 = *(const float4*)&Xt2[kk][r0];
            float4 k4 = *(const float4*)&Ws2[kk][c0];
            float4 v4 = *(const float4*)&Ws2[kk][128 + c0];
            #pragma unroll
            for (int i = 0; i < 4; ++i) {
                float xi = (i==0)?x4.x:(i==1)?x4.y:(i==2)?x4.z:x4.w;
                ak[i][0] = fmaf(xi, k4.x, ak[i][0]); ak[i][1] = fmaf(xi, k4.y, ak[i][1]);
                ak[i][2] = fmaf(xi, k4.z, ak[i][2]); ak[i][3] = fmaf(xi, k4.w, ak[i][3]);
                av[i][0] = fmaf(xi, v4.x, av[i][0]); av[i][1] = fmaf(xi, v4.y, av[i][1]);
                av[i][2] = fmaf(xi, v4.z, av[i][2]); av[i][3] = fmaf(xi, v4.w, av[i][3]);
            }
        }
        __syncthreads();
    }
    float4 bk4 = *(const float4*)(bk + c0);
    float4 bv4 = *(const float4*)(bv + c0);
    #pragma unroll
    for (int i = 0; i < 4; ++i) {
        int row = rowbase + r0 + i;
        float4 ok, ov;
        ok.x = ak[i][0]+bk4.x; ok.y = ak[i][1]+bk4.y; ok.z = ak[i][2]+bk4.z; ok.w = ak[i][3]+bk4.w;
        ov.x = av[i][0]+bv4.x; ov.y = av[i][1]+bv4.y; ov.z = av[i][2]+bv4.z; ov.w = av[i][3]+bv4.w;
        *(float4*)(Yk + (long)row * 128 + c0) = ok;
        *(float4*)(Yv + (long)row * 128 + c0) = ov;
    }
}

// ---------------- uber: W' = emb_w @ wq_w (blocks 0-9), b' = emb_b@wq_w + wq_b (block 10) ----
__global__ __launch_bounds__(256) void pre0_k(const float* __restrict__ emb_w, const float* __restrict__ emb_b,
                                              const float* __restrict__ wq_w, const float* __restrict__ wq_b,
                                              const float* __restrict__ zeros,
                                              float* __restrict__ Wp, float* __restrict__ bp)
{
    if (blockIdx.x == 10) {
        int n = threadIdx.x;
        if (n < 128) {
            float a0 = 0.f, a1 = 0.f, a2 = 0.f, a3 = 0.f;
            for (int k = 0; k < 128; k += 4) {
                a0 = fmaf(emb_b[k+0], wq_w[(k+0)*128 + n], a0);
                a1 = fmaf(emb_b[k+1], wq_w[(k+1)*128 + n], a1);
                a2 = fmaf(emb_b[k+2], wq_w[(k+2)*128 + n], a2);
                a3 = fmaf(emb_b[k+3], wq_w[(k+3)*128 + n], a3);
            }
            bp[n] = (a0 + a1) + (a2 + a3) + wq_b[n];
        }
        return;
    }
    gemm_body<false,false>(emb_w, nullptr, nullptr, nullptr, wq_w, zeros, Wp, 128, blockIdx.x * 32);
}

// ---------------- uber: Q gemm (0-249, K=320) + K/V dual gemm (250-499) ----------------
__global__ __launch_bounds__(256) void qkv_k(const float* __restrict__ PE, const float* __restrict__ Wp,
                                             const float* __restrict__ bp, const float* __restrict__ PFX,
                                             const float* __restrict__ wk_w, const float* __restrict__ wv_w,
                                             const float* __restrict__ wk_b, const float* __restrict__ wv_b,
                                             float* __restrict__ Qo, float* __restrict__ Ko, float* __restrict__ Vo)
{
    if (blockIdx.x < 250)
        gemm_body<false,false>(PE, nullptr, nullptr, nullptr, Wp, bp, Qo, 320, blockIdx.x * 32);
    else
        kv_body(PFX, wk_w, wv_w, wk_b, wv_b, Ko, Vo, (blockIdx.x - 250) * 32);
}

// ---------------- uber: wo gemm w/ split-merge (0-249) + jc gemm (250-265) ----------------
__global__ __launch_bounds__(256) void wojc_k(const float* __restrict__ Opart, const float* __restrict__ mp,
                                              const float* __restrict__ lp, const float* __restrict__ wo_w,
                                              const float* __restrict__ wo_b, float* __restrict__ Att,
                                              const float* __restrict__ CF, const float* __restrict__ jc_w,
                                              const float* __restrict__ jc_b, float* __restrict__ Cj)
{
    if (blockIdx.x < 250)
        gemm_body<false,true>(Opart, Opart + 1024000, mp, lp, wo_w, wo_b, Att, 128, blockIdx.x * 32);
    else
        gemm_body<true,false>(CF, nullptr, nullptr, nullptr, jc_w, jc_b, Cj, 128, (blockIdx.x - 250) * 32);
}

// ---------------- jp gemm ----------------
__global__ __launch_bounds__(256) void jp_k(const float* __restrict__ Att, const float* __restrict__ jp_w,
                                            const float* __restrict__ jp_b, float* __restrict__ P)
{
    gemm_body<true,false>(Att, nullptr, nullptr, nullptr, jp_w, jp_b, P, 128, blockIdx.x * 32);
}

// ---------------- flash attention v3 (fp32), TQ=32, TK=64, split x2, 128 threads ----------------
// Thread: 4 q-rows (rg*4+i) x 4 k-cols (cl+16j) QK; 4 rows x 8 dcols PV.
// K AND V register-prefetched across barriers (global loads in flight under
// compute); P transposed through Pt for b128 PV reads. 59.9 KB LDS -> 2 blk/CU.
__global__ __launch_bounds__(128) void flash3_k(const float* __restrict__ Q, const float* __restrict__ Kg,
                                                const float* __restrict__ Vg, float* __restrict__ Opart,
                                                float* __restrict__ mpart, float* __restrict__ lpart)
{
    __shared__ __align__(16) float Qs[32][132];
    __shared__ __align__(16) float KVs[64][132];
    __shared__ __align__(16) float Pt[64][36];
    const int t  = threadIdx.x;
    const int rg = t >> 4;        // 0..7 -> rows rg*4..rg*4+3
    const int cl = t & 15;        // cols cl+16j
    const int qt = blockIdx.x, sp = blockIdx.y, b = blockIdx.z;
    const int q0 = qt * 32;
    const float SCALE = 0.08838834764831845f;   // 1/sqrt(128)
    const float L2E   = 1.4426950408889634f;

    #pragma unroll
    for (int u = 0; u < 8; ++u) {   // Q tile 32x128
        int s = t + u * 128, r = s >> 5, cb = (s & 31) << 2;
        float4 v = make_float4(0.f,0.f,0.f,0.f);
        if (q0 + r < LP) v = *(const float4*)(Q + ((long)b * LP + q0 + r) * 128 + cb);
        Qs[r][cb] = v.x; Qs[r][cb+1] = v.y; Qs[r][cb+2] = v.z; Qs[r][cb+3] = v.w;
    }
    float m_i[4] = {-3.0e38f,-3.0e38f,-3.0e38f,-3.0e38f};
    float l_i[4] = {0.f,0.f,0.f,0.f};
    float Oa[4][8] = {};
    float4 kreg[16], vreg[16];
    {   // prologue: K prefetch for first kt
        const int key0 = sp * 512;
        #pragma unroll
        for (int u = 0; u < 16; ++u) {
            int s = t + u * 128, r = s >> 5, cb = (s & 31) << 2;
            kreg[u] = make_float4(0.f,0.f,0.f,0.f);
            if (key0 + r < LP) kreg[u] = *(const float4*)(Kg + ((long)b * LP + key0 + r) * 128 + cb);
        }
    }
    for (int kt = sp * 8; kt < sp * 8 + 8; ++kt) {
        const int key0 = kt * 64;
        __syncthreads();                               // (A) prev PV done with KVs
        #pragma unroll
        for (int u = 0; u < 16; ++u) {                 // K regs -> LDS
            int s = t + u * 128, r = s >> 5, cb = (s & 31) << 2;
            KVs[r][cb] = kreg[u].x; KVs[r][cb+1] = kreg[u].y;
            KVs[r][cb+2] = kreg[u].z; KVs[r][cb+3] = kreg[u].w;
        }
        __syncthreads();                               // (B) K visible
        #pragma unroll
        for (int u = 0; u < 16; ++u) {                 // V prefetch (drains under QK)
            int s = t + u * 128, r = s >> 5, cb = (s & 31) << 2;
            vreg[u] = make_float4(0.f,0.f,0.f,0.f);
            if (key0 + r < LP) vreg[u] = *(const float4*)(Vg + ((long)b * LP + key0 + r) * 128 + cb);
        }
        float sacc[4][4] = {};
        #pragma unroll 4
        for (int d4 = 0; d4 < 32; ++d4) {
            float4 q0v = *(const float4*)&Qs[rg*4+0][d4<<2];
            float4 q1v = *(const float4*)&Qs[rg*4+1][d4<<2];
            float4 q2v = *(const float4*)&Qs[rg*4+2][d4<<2];
            float4 q3v = *(const float4*)&Qs[rg*4+3][d4<<2];
            #pragma unroll
            for (int j = 0; j < 4; ++j) {
                float4 kv = *(const float4*)&KVs[cl + (j<<4)][d4<<2];
                sacc[0][j] += q0v.x*kv.x + q0v.y*kv.y + q0v.z*kv.z + q0v.w*kv.w;
                sacc[1][j] += q1v.x*kv.x + q1v.y*kv.y + q1v.z*kv.z + q1v.w*kv.w;
                sacc[2][j] += q2v.x*kv.x + q2v.y*kv.y + q2v.z*kv.z + q2v.w*kv.w;
                sacc[3][j] += q3v.x*kv.x + q3v.y*kv.y + q3v.z*kv.z + q3v.w*kv.w;
            }
        }
        #pragma unroll
        for (int j = 0; j < 4; ++j) {                  // scale + mask
            bool valid = (key0 + cl + (j<<4)) < LP;
            #pragma unroll
            for (int i = 0; i < 4; ++i) {
                float sv = sacc[i][j] * SCALE;
                sacc[i][j] = valid ? sv : -3.0e38f;
            }
        }
        #pragma unroll
        for (int i = 0; i < 4; ++i) {                  // online softmax (16-lane row groups)
            float tm = fmaxf(fmaxf(sacc[i][0], sacc[i][1]), fmaxf(sacc[i][2], sacc[i][3]));
            tm = fmaxf(tm, __shfl_xor(tm, 1));
            tm = fmaxf(tm, __shfl_xor(tm, 2));
            tm = fmaxf(tm, __shfl_xor(tm, 4));
            tm = fmaxf(tm, __shfl_xor(tm, 8));
            float mnew = fmaxf(m_i[i], tm);
            float alpha = exp2f((m_i[i] - mnew) * L2E);
            float ps = 0.f;
            #pragma unroll
            for (int j = 0; j < 4; ++j) {
                float p = exp2f((sacc[i][j] - mnew) * L2E);
                sacc[i][j] = p;
                ps += p;
            }
            ps += __shfl_xor(ps, 1);
            ps += __shfl_xor(ps, 2);
            ps += __shfl_xor(ps, 4);
            ps += __shfl_xor(ps, 8);
            l_i[i] = l_i[i] * alpha + ps;
            m_i[i] = mnew;
            #pragma unroll
            for (int j = 0; j < 8; ++j) Oa[i][j] *= alpha;
        }
        __syncthreads();                               // (C) K reads done
        #pragma unroll
        for (int u = 0; u < 16; ++u) {                 // V regs -> LDS (overwrite K)
            int s = t + u * 128, r = s >> 5, cb = (s & 31) << 2;
            KVs[r][cb] = vreg[u].x; KVs[r][cb+1] = vreg[u].y;
            KVs[r][cb+2] = vreg[u].z; KVs[r][cb+3] = vreg[u].w;
        }
        #pragma unroll
        for (int j = 0; j < 4; ++j)                    // P -> Pt[c][rows]
            *(float4*)&Pt[cl + (j<<4)][rg*4] =
                make_float4(sacc[0][j], sacc[1][j], sacc[2][j], sacc[3][j]);
        __syncthreads();                               // (D) V + Pt visible
        if (kt + 1 < sp * 8 + 8) {                     // K prefetch kt+1 (drains under PV)
            const int kn0 = (kt + 1) * 64;
            #pragma unroll
            for (int u = 0; u < 16; ++u) {
                int s = t + u * 128, r = s >> 5, cb = (s & 31) << 2;
                kreg[u] = make_float4(0.f,0.f,0.f,0.f);
                if (kn0 + r < LP) kreg[u] = *(const float4*)(Kg + ((long)b * LP + kn0 + r) * 128 + cb);
            }
        }
        #pragma unroll 2
        for (int c = 0; c < 64; ++c) {                 // PV
            float4 p4 = *(const float4*)&Pt[c][rg*4];
            float4 va = *(const float4*)&KVs[c][cl*4];
            float4 vb = *(const float4*)&KVs[c][64 + cl*4];
            Oa[0][0] = fmaf(p4.x, va.x, Oa[0][0]); Oa[0][1] = fmaf(p4.x, va.y, Oa[0][1]);
            Oa[0][2] = fmaf(p4.x, va.z, Oa[0][2]); Oa[0][3] = fmaf(p4.x, va.w, Oa[0][3]);
            Oa[0][4] = fmaf(p4.x, vb.x, Oa[0][4]); Oa[0][5] = fmaf(p4.x, vb.y, Oa[0][5]);
            Oa[0][6] = fmaf(p4.x, vb.z, Oa[0][6]); Oa[0][7] = fmaf(p4.x, vb.w, Oa[0][7]);
            Oa[1][0] = fmaf(p4.y, va.x, Oa[1][0]); Oa[1][1] = fmaf(p4.y, va.y, Oa[1][1]);
            Oa[1][2] = fmaf(p4.y, va.z, Oa[1][2]); Oa[1][3] = fmaf(p4.y, va.w, Oa[1][3]);
            Oa[1][4] = fmaf(p4.y, vb.x, Oa[1][4]); Oa[1][5] = fmaf(p4.y, vb.y, Oa[1][5]);
            Oa[1][6] = fmaf(p4.y, vb.z, Oa[1][6]); Oa[1][7] = fmaf(p4.y, vb.w, Oa[1][7]);
            Oa[2][0] = fmaf(p4.z, va.x, Oa[2][0]); Oa[2][1] = fmaf(p4.z, va.y, Oa[2][1]);
            Oa[2][2] = fmaf(p4.z, va.z, Oa[2][2]); Oa[2][3] = fmaf(p4.z, va.w, Oa[2][3]);
            Oa[2][4] = fmaf(p4.z, vb.x, Oa[2][4]); Oa[2][5] = fmaf(p4.z, vb.y, Oa[2][5]);
            Oa[2][6] = fmaf(p4.z, vb.z, Oa[2][6]); Oa[2][7] = fmaf(p4.z, vb.w, Oa[2][7]);
            Oa[3][0] = fmaf(p4.w, va.x, Oa[3][0]); Oa[3][1] = fmaf(p4.w, va.y, Oa[3][1]);
            Oa[3][2] = fmaf(p4.w, va.z, Oa[3][2]); Oa[3][3] = fmaf(p4.w, va.w, Oa[3][3]);
            Oa[3][4] = fmaf(p4.w, vb.x, Oa[3][4]); Oa[3][5] = fmaf(p4.w, vb.y, Oa[3][5]);
            Oa[3][6] = fmaf(p4.w, vb.z, Oa[3][6]); Oa[3][7] = fmaf(p4.w, vb.w, Oa[3][7]);
        }
    }
    #pragma unroll
    for (int i = 0; i < 4; ++i) {
        int row = q0 + rg * 4 + i;
        if (row < LP) {
            long base = (((long)sp * 8 + b) * LP + row) * 128;
            *(float4*)(Opart + base + cl*4)      = make_float4(Oa[i][0], Oa[i][1], Oa[i][2], Oa[i][3]);
            *(float4*)(Opart + base + 64 + cl*4) = make_float4(Oa[i][4], Oa[i][5], Oa[i][6], Oa[i][7]);
            if (cl == 0) {
                mpart[((long)sp * 8 + b) * LP + row] = m_i[i];
                lpart[((long)sp * 8 + b) * LP + row] = l_i[i];
            }
        }
    }
}

// -------- fused: A = sigmoid(P C^T) in LDS + Asum + tanh outer-product reduce --------
__global__ __launch_bounds__(256) void sigcp_k(const float* __restrict__ P, const float* __restrict__ Cj,
                                               const float* __restrict__ pf, const float* __restrict__ cf,
                                               float* __restrict__ Asum, float* __restrict__ cpe)
{
    __shared__ __align__(16) float Psh[32][132];
    __shared__ __align__(16) float Csh[64][132];
    __shared__ float Ash[32][64];
    __shared__ float red[256];
    const int t  = threadIdx.x;
    const int tr = t >> 4, tc = t & 15;
    const int i0 = blockIdx.x * 32;
    const int b  = blockIdx.y;
    #pragma unroll
    for (int u = 0; u < 4; ++u) {
        int s = t + u * 256, r = s >> 5, cb = (s & 31) << 2;
        float4 v = make_float4(0.f,0.f,0.f,0.f);
        if (i0 + r < LP) v = *(const float4*)(P + ((long)b * LP + i0 + r) * 128 + cb);
        Psh[r][cb] = v.x; Psh[r][cb+1] = v.y; Psh[r][cb+2] = v.z; Psh[r][cb+3] = v.w;
    }
    #pragma unroll
    for (int u = 0; u < 8; ++u) {
        int s = t + u * 256, r = s >> 5, cb = (s & 31) << 2;
        float4 v = *(const float4*)(Cj + ((long)b * NCMP + r) * 128 + cb);
        Csh[r][cb] = v.x; Csh[r][cb+1] = v.y; Csh[r][cb+2] = v.z; Csh[r][cb+3] = v.w;
    }
    __syncthreads();
    float sacc[2][4] = {};
    #pragma unroll 4
    for (int d4 = 0; d4 < 32; ++d4) {
        float4 p0 = *(const float4*)&Psh[2*tr][d4<<2];
        float4 p1 = *(const float4*)&Psh[2*tr+1][d4<<2];
        #pragma unroll
        for (int j = 0; j < 4; ++j) {
            float4 cv = *(const float4*)&Csh[tc + (j<<4)][d4<<2];
            sacc[0][j] += p0.x*cv.x + p0.y*cv.y + p0.z*cv.z + p0.w*cv.w;
            sacc[1][j] += p1.x*cv.x + p1.y*cv.y + p1.z*cv.z + p1.w*cv.w;
        }
    }
    const float L2E = 1.4426950408889634f;
    float lsum = 0.f;
    #pragma unroll
    for (int i = 0; i < 2; ++i) {
        int gi = i0 + 2*tr + i;
        #pragma unroll
        for (int j = 0; j < 4; ++j) {
            float sg = rcp_fast(1.f + exp2f(-sacc[i][j] * L2E));
            if (gi < LP) { Ash[2*tr+i][tc + (j<<4)] = sg; lsum += sg; }
        }
    }
    red[t] = lsum;
    __syncthreads();
    for (int off = 128; off > 0; off >>= 1) {
        if (t < off) red[t] += red[t + off];
        __syncthreads();
    }
    if (t == 0) atomicAdd(Asum + b, red[0]);
    __syncthreads();
    #pragma unroll
    for (int u = 0; u < 8; ++u) {                      // reload Csh with raw compound feats
        int s = t + u * 256, r = s >> 5, cb = (s & 31) << 2;
        float4 v = *(const float4*)(cf + ((long)b * NCMP + r) * 128 + cb);
        Csh[r][cb] = v.x; Csh[r][cb+1] = v.y; Csh[r][cb+2] = v.z; Csh[r][cb+3] = v.w;
    }
    __syncthreads();
    const float TWO_L2E = 2.8853900817779268f;   // 2*log2(e)
    const int d  = t & 127;
    const int kh = t >> 7;
    const int iiN = (LP - i0 < 32) ? (LP - i0) : 32;
    float acc = 0.f;
    for (int ii = 0; ii < iiN; ++ii) {
        float pv  = pf[((long)b * LP + i0 + ii) * 128 + d];
        float ptl = pv * TWO_L2E;
        #pragma unroll
        for (int kk = 0; kk < 32; ++kk) {
            int k = (kh << 5) + kk;
            float e  = exp2f(ptl * Csh[k][d]);          // exp(2x)
            float th = 1.f - 2.f * rcp_fast(e + 1.f);   // tanh(x)
            acc = fmaf(th, Ash[ii][k], acc);
        }
    }
    red[t] = acc;
    __syncthreads();
    if (t < 128) atomicAdd(cpe + (long)b * 128 + t, red[t] + red[t + 128]);
}

// ---------------- c1 direct: h1 = relu((cpe/Asum) @ c1_w + b1), 32 blocks ----------------
__global__ __launch_bounds__(256) void c1h_k(const float* __restrict__ cpe, const float* __restrict__ Asum,
                                             const float* __restrict__ W, const float* __restrict__ bias,
                                             float* __restrict__ h1)
{
    __shared__ float sc[8][128];
    const int t = threadIdx.x;
    #pragma unroll
    for (int u = 0; u < 4; ++u) {
        int idx = t + u * 256;
        sc[idx >> 7][idx & 127] = cpe[idx] * rcp_fast(Asum[idx >> 7]);
    }
    __syncthreads();
    const int b = t >> 5, n = blockIdx.x * 32 + (t & 31);
    float a0 = 0.f, a1 = 0.f, a2 = 0.f, a3 = 0.f;
    #pragma unroll 8
    for (int k = 0; k < 128; k += 4) {
        a0 = fmaf(sc[b][k+0], W[(long)(k+0)*1024 + n], a0);
        a1 = fmaf(sc[b][k+1], W[(long)(k+1)*1024 + n], a1);
        a2 = fmaf(sc[b][k+2], W[(long)(k+2)*1024 + n], a2);
        a3 = fmaf(sc[b][k+3], W[(long)(k+3)*1024 + n], a3);
    }
    h1[b * 1024 + n] = fmaxf((a0 + a1) + (a2 + a3) + bias[n], 0.f);
}

// ---------------- c2 split-K partials: 64 blocks ----------------
__global__ __launch_bounds__(256) void c2_part_k(const float* __restrict__ in, const float* __restrict__ W,
                                                 float* __restrict__ part)
{
    __shared__ float ins[8][16];
    const int t = threadIdx.x, ks = blockIdx.x, k0 = ks * 16;
    if (t < 128) {
        int b = t >> 4, kk = t & 15;
        ins[b][kk] = in[b * 1024 + k0 + kk];
    }
    __syncthreads();
    const int n = (t & 63) * 4 + (t >> 6) * 256;
    float4 acc[8] = {};
    #pragma unroll
    for (int kk = 0; kk < 16; ++kk) {
        float4 w4 = *(const float4*)(W + (long)(k0 + kk) * 1024 + n);
        #pragma unroll
        for (int b = 0; b < 8; ++b) {
            float s = ins[b][kk];
            acc[b].x = fmaf(s, w4.x, acc[b].x); acc[b].y = fmaf(s, w4.y, acc[b].y);
            acc[b].z = fmaf(s, w4.z, acc[b].z); acc[b].w = fmaf(s, w4.w, acc[b].w);
        }
    }
    #pragma unroll
    for (int b = 0; b < 8; ++b)
        *(float4*)(part + ((long)(ks * 8 + b)) * 1024 + n) = acc[b];
}

// ------- c3+c4 fused: h2=relu(sum part2 + b2); h3=relu(h2@c3_w+b3); out[b]=h3.c4_w+b4 -------
__global__ __launch_bounds__(256) void c3m_k(const float* __restrict__ part2, const float* __restrict__ c2_b,
                                             const float* __restrict__ c3_w, const float* __restrict__ c3_b,
                                             const float* __restrict__ c4_w, const float* __restrict__ c4_b,
                                             float* __restrict__ out)
{
    __shared__ float Hs[1024];
    __shared__ float red[256];
    const int t = threadIdx.x, b = blockIdx.x;
    float4 acc4 = make_float4(0.f,0.f,0.f,0.f);
    #pragma unroll 4
    for (int ks = 0; ks < 64; ++ks) {
        float4 p = *(const float4*)(part2 + ((long)(ks * 8 + b)) * 1024 + t * 4);
        acc4.x += p.x; acc4.y += p.y; acc4.z += p.z; acc4.w += p.w;
    }
    {
        float4 bb = *(const float4*)(c2_b + t * 4);
        Hs[t*4+0] = fmaxf(acc4.x + bb.x, 0.f);
        Hs[t*4+1] = fmaxf(acc4.y + bb.y, 0.f);
        Hs[t*4+2] = fmaxf(acc4.z + bb.z, 0.f);
        Hs[t*4+3] = fmaxf(acc4.w + bb.w, 0.f);
    }
    __syncthreads();
    float a0 = 0.f, a1 = 0.f, a2 = 0.f, a3 = 0.f;
    #pragma unroll 8
    for (int k = 0; k < 1024; k += 4) {
        a0 = fmaf(Hs[k+0], c3_w[(long)(k+0)*256 + t], a0);
        a1 = fmaf(Hs[k+1], c3_w[(long)(k+1)*256 + t], a1);
        a2 = fmaf(Hs[k+2], c3_w[(long)(k+2)*256 + t], a2);
        a3 = fmaf(Hs[k+3], c3_w[(long)(k+3)*256 + t], a3);
    }
    float h3v = fmaxf((a0 + a1) + (a2 + a3) + c3_b[t], 0.f);
    red[t] = h3v * c4_w[t];
    __syncthreads();
    for (int off = 128; off > 0; off >>= 1) {
        if (t < off) red[t] += red[t + off];
        __syncthreads();
    }
    if (t == 0) out[b] = red[0] + c4_b[0];
}

extern "C" void kernel_launch(void* const* d_in, const int* in_sizes, int n_in,
                              void* d_out, int out_size, void* d_ws, size_t ws_size,
                              hipStream_t stream)
{
    const float* PE   = (const float*)d_in[0];
    const float* PFX  = (const float*)d_in[1];
    const float* CF   = (const float*)d_in[2];
    const float* emb_w = (const float*)d_in[3];  const float* emb_b = (const float*)d_in[4];
    const float* wq_w  = (const float*)d_in[5];  const float* wq_b  = (const float*)d_in[6];
    const float* wk_w  = (const float*)d_in[7];  const float* wk_b  = (const float*)d_in[8];
    const float* wv_w  = (const float*)d_in[9];  const float* wv_b  = (const float*)d_in[10];
    const float* wo_w  = (const float*)d_in[11]; const float* wo_b  = (const float*)d_in[12];
    const float* jp_w  = (const float*)d_in[13]; const float* jp_b  = (const float*)d_in[14];
    const float* jc_w  = (const float*)d_in[15]; const float* jc_b  = (const float*)d_in[16];
    const float* c1_w  = (const float*)d_in[17]; const float* c1_b  = (const float*)d_in[18];
    const float* c2_w  = (const float*)d_in[19]; const float* c2_b  = (const float*)d_in[20];
    const float* c3_w  = (const float*)d_in[21]; const float* c3_b  = (const float*)d_in[22];
    const float* c4_w  = (const float*)d_in[23]; const float* c4_b  = (const float*)d_in[24];

    float* ws     = (float*)d_ws;
    float* bufQ   = ws;                    // 1,024,000
    float* bufK   = bufQ   + 1024000;      // 1,024,000
    float* bufV   = bufK   + 1024000;      // 1,024,000
    float* bufAtt = bufV   + 1024000;      // 1,024,000 (protein_feats)
    float* bufP   = bufAtt + 1024000;      // 1,024,000
    float* bufC   = bufP   + 1024000;      //    65,536
    float* Opart  = bufC   + 65536;        // 2,048,000 (flash partials; later c2 partials)
    float* mpart  = Opart  + 2048000;      //    16,000
    float* lpart  = mpart  + 16000;        //    16,000
    float* Asum   = lpart  + 16000;        //         8
    float* cpe    = Asum   + 8;            //     1,024
    float* zeros  = cpe    + 1024;         //       128
    float* bprime = zeros  + 128;          //       128
    float* bufWp  = bprime + 128;          //    40,960  (emb_w @ wq_w)
    float* h1     = bufWp  + 40960;        //     8,192
    float* part2  = Opart;                 //   524,288 (aliases Opart, dead after wojc)
    // total ~7.3M floats = ~29.2 MB

    hipMemsetAsync(Asum, 0, (8 + 1024 + 128) * sizeof(float), stream);   // Asum, cpe, zeros

    pre0_k<<<11, 256, 0, stream>>>(emb_w, emb_b, wq_w, wq_b, zeros, bufWp, bprime);
    qkv_k<<<500, 256, 0, stream>>>(PE, bufWp, bprime, PFX, wk_w, wv_w, wk_b, wv_b,
                                   bufQ, bufK, bufV);
    flash3_k<<<dim3(32, 2, 8), 128, 0, stream>>>(bufQ, bufK, bufV, Opart, mpart, lpart);
    wojc_k<<<266, 256, 0, stream>>>(Opart, mpart, lpart, wo_w, wo_b, bufAtt,
                                    CF, jc_w, jc_b, bufC);
    jp_k<<<250, 256, 0, stream>>>(bufAtt, jp_w, jp_b, bufP);
    sigcp_k<<<dim3(32, 8), 256, 0, stream>>>(bufP, bufC, bufAtt, CF, Asum, cpe);
    c1h_k<<<32, 256, 0, stream>>>(cpe, Asum, c1_w, c1_b, h1);
    c2_part_k<<<64, 256, 0, stream>>>(h1, c2_w, part2);
    c3m_k<<<8, 256, 0, stream>>>(part2, c2_b, c3_w, c3_b, c4_w, c4_b, (float*)d_out);
}